// Round 1
// 278.821 us; speedup vs baseline: 1.0529x; 1.0529x over previous
//
#include <hip/hip_runtime.h>

// FilteredNoise: DDSP filtered noise, FFT-free.
// zp[d] = (1/129)(fr0 + 2*sum_{k=1..64} fr_k cos(2*pi*k*d/129)), even-symmetric
// wir[j] = hann_periodic(j,129) * zp[(j-64) mod 129]; j=128 tap dropped (win=5.9e-4)
// out[b,64*fp+r] = sum_{dd=0..2} sum_s n[fp-dd][s] * wir[fp-dd][64*dd+r-s]
//
// This revision (layout pass):
//  - conv mapping transposed: chunk = tid&15, t = tid>>4 -> each 8-lane LDS phase
//    spans 8 distinct frames q; with ODD quad strides (wirP 49 quads, nS 17 quads)
//    bank-quad = (q + c) mod 8 is a permutation -> zero bank conflicts, no swizzle.
//  - wirP quad-aligned: tap k stored at float k+32, row = 49 quads (196 floats);
//    every window read is one aligned ds_read_b128. LDS total 19536 B -> 8 blk/CU.
//  - wave-uniform triangle skip: wave0 skips dd0 s4>=8 (taps<1 -> 0),
//    wave1 skips dd2 s4<8 (taps>127 -> 0). 40 instead of 48 inner blocks, no divergence.

#define NB 64
#define FTOT 4097
#define FCL 65
#define SAMPLES 262144
#define OUT_FRAMES 4096
#define G 16                     // output frames per block
#define NF (G + 2)               // staged frames (2 overlap)
#define NSTRIDE 68               // nS row stride: 17 quads (odd -> conflict-free phases)
#define PW 196                   // wirP row stride: 49 quads (odd); data floats [33..159]
#define BLOCKS_PER_B (OUT_FRAMES / G)   // 256

__device__ __forceinline__ float mod_sigmoid(float x) {
    float s = 1.0f / (1.0f + __expf(-x));
    return 2.0f * __expf(2.302585092994046f * __logf(s)) + 1e-7f;   // 2*s^ln(10)+1e-7
}

__device__ __forceinline__ float rdlane(float v, int k) {
    return __int_as_float(__builtin_amdgcn_readlane(__float_as_int(v), k));
}

// One dd-pass of the conv: 8 outputs (r = r0..r0+7), rolling 3-quad w-window.
// wq points at quad A(s4=0) = row_base_quad + 8 + 16*dd + 2*t.
// Iteration s4 uses quads A-1 (W0, fresh read), A (W1), A+1 (W2), where A = A0 - s4.
// a[j] += n[4*s4+i] * w[tap0 + j - i], tap0 = 64*dd + r0 - 4*s4;
// w float index = tap + 32; quad A-1 starts at tap0 - 4 -> w[] slot 4 + j - i.
template<int S0, int S1>
__device__ __forceinline__ void conv_dd(const float4* __restrict__ wq,
                                        const float4* __restrict__ nq,
                                        float a[8]) {
    float4 W1 = wq[-S0];
    float4 W2 = wq[-S0 + 1];
    #pragma unroll
    for (int s4 = S0; s4 < S1; ++s4) {
        float4 W0 = wq[-s4 - 1];                 // single aligned ds_read_b128
        float4 n4 = nq[s4];
        float w[12] = {W0.x, W0.y, W0.z, W0.w,
                       W1.x, W1.y, W1.z, W1.w,
                       W2.x, W2.y, W2.z, W2.w};
        float nv[4] = {n4.x, n4.y, n4.z, n4.w};
        #pragma unroll
        for (int i = 0; i < 4; ++i)
            #pragma unroll
            for (int j = 0; j < 8; ++j)
                a[j] = __builtin_fmaf(nv[i], w[4 + j - i], a[j]);
        W2 = W1; W1 = W0;                        // roll window (renamed regs, free)
    }
}

__global__ __launch_bounds__(128, 4) void fn_kernel(
    const float* __restrict__ coeff,   // (64, 4097, 65)
    const float* __restrict__ noise,   // (64, 4097, 64)
    float* __restrict__ out)           // (64, 262144)
{
    __shared__ __align__(16) float costab[132];          // cos(2*pi*m/129), m<=128
    __shared__ __align__(16) float nS[NF * NSTRIDE];     // noise*2-1 (zero f<0)
    __shared__ __align__(16) float wirP[NF * PW];        // tap k at float k+32

    const int tid  = threadIdx.x;
    const int lane = tid & 63;
    const int wv   = tid >> 6;                           // wave id 0..1
    const int blk  = blockIdx.x;
    const int b    = blk / BLOCKS_PER_B;
    const int cg   = blk % BLOCKS_PER_B;
    const int fp0  = cg * G;
    const int fbase = fp0 - 2;

    // zero wirP (pads must be 0; scatter after barrier overwrites data region)
    for (int i = tid; i < NF * PW / 4; i += 128)
        ((float4*)wirP)[i] = make_float4(0.f, 0.f, 0.f, 0.f);
    for (int i = tid; i < 129; i += 128)
        costab[i] = __cosf(6.283185307179586f * (float)i * (1.0f / 129.0f));

    // stage noise (float4), zero where frame < 0
    for (int i = tid; i < NF * 16; i += 128) {
        int q = i >> 4, g = i & 15;
        int f = fbase + q;
        float4 v = make_float4(0.f, 0.f, 0.f, 0.f);
        if (f >= 0) {
            const float4* src = (const float4*)(noise + ((size_t)b * FTOT + f) * 64);
            float4 u = src[g];
            v = make_float4(2.f*u.x-1.f, 2.f*u.y-1.f, 2.f*u.z-1.f, 2.f*u.w-1.f);
        }
        *(float4*)&nS[q * NSTRIDE + 4 * g] = v;
    }

    // preload this wave's 9 frame spectra (frames wv, wv+2, ..., wv+16)
    float frv[9], f64v[9];
    #pragma unroll
    for (int i = 0; i < 9; ++i) {
        int f = fbase + wv + 2 * i;
        if (f < 0) f = 0;                        // garbage wir nulled via n=0
        const float* row = coeff + ((size_t)b * FTOT + f) * FCL;
        frv[i]  = row[lane];
        f64v[i] = row[64];
    }
    #pragma unroll
    for (int i = 0; i < 9; ++i) {
        frv[i]  = mod_sigmoid(frv[i]);
        f64v[i] = mod_sigmoid(f64v[i]);
    }

    __syncthreads();   // wirP zeros + nS + costab visible

    // transform: shared Chebyshev recurrence across the wave's 9 frames
    {
        float c  = costab[lane];
        float c2 = 2.0f * c;
        float cp = 1.0f;         // cos(0)
        float ck = c;            // cos(theta)
        float S[9];
        #pragma unroll
        for (int i = 0; i < 9; ++i) S[i] = 0.5f * rdlane(frv[i], 0);   // 0.5*fr0
        #pragma unroll 8
        for (int k = 1; k < 64; ++k) {
            #pragma unroll
            for (int i = 0; i < 9; ++i)
                S[i] = __builtin_fmaf(rdlane(frv[i], k), ck, S[i]);
            float cn = __builtin_fmaf(c2, ck, -cp);
            cp = ck; ck = cn;
        }
        // k = 64 term: ck = cos(64*theta)
        #pragma unroll
        for (int i = 0; i < 9; ++i)
            S[i] = __builtin_fmaf(f64v[i], ck, S[i]);
        // window + scatter: zp = 2*S/129; taps k = 64 +- lane at float (k+32) = 96 +- lane
        float w1f = 0.5f - 0.5f * costab[64 + lane];
        float w2f = 0.5f - 0.5f * costab[64 - lane];
        #pragma unroll
        for (int i = 0; i < 9; ++i) {
            int fi = wv + 2 * i;
            float zp = S[i] * (2.0f / 129.0f);
            wirP[fi * PW + 96 + lane] = w1f * zp;
            wirP[fi * PW + 96 - lane] = w2f * zp;
        }
    }
    __syncthreads();

    // conv + OLA: thread = (chunk = output frame, t = sample octet), 8 samples each
    {
        const int chunk = tid & 15;              // output frame within block
        const int t     = tid >> 4;              // r0 = 8*t
        float a[8];
        #pragma unroll
        for (int j = 0; j < 8; ++j) a[j] = 0.0f;

        // dd = 0: frame fp (q = chunk+2). wave0 (r0<=24): taps r0+7-4*s4 < 1 for s4>=8 -> skip.
        {
            const int q = chunk + 2;
            const float4* wq = (const float4*)&wirP[q * PW] + (8 + 2 * t);
            const float4* nq = (const float4*)&nS[q * NSTRIDE];
            if (wv == 0) conv_dd<0, 8>(wq, nq, a);
            else         conv_dd<0, 16>(wq, nq, a);
        }
        // dd = 1: frame fp-1 (q = chunk+1), dense
        {
            const int q = chunk + 1;
            const float4* wq = (const float4*)&wirP[q * PW] + (24 + 2 * t);
            const float4* nq = (const float4*)&nS[q * NSTRIDE];
            conv_dd<0, 16>(wq, nq, a);
        }
        // dd = 2: frame fp-2 (q = chunk). wave1 (r0>=32): taps 128+r0-4*s4-3 > 127 for s4<8 -> skip.
        {
            const int q = chunk;
            const float4* wq = (const float4*)&wirP[q * PW] + (40 + 2 * t);
            const float4* nq = (const float4*)&nS[q * NSTRIDE];
            if (wv == 0) conv_dd<0, 16>(wq, nq, a);
            else         conv_dd<8, 16>(wq, nq, a);
        }

        float* op = &out[(size_t)b * SAMPLES + (size_t)(fp0 + chunk) * 64 + t * 8];
        *(float4*)op       = make_float4(a[0], a[1], a[2], a[3]);
        *(float4*)(op + 4) = make_float4(a[4], a[5], a[6], a[7]);
    }
}

extern "C" void kernel_launch(void* const* d_in, const int* in_sizes, int n_in,
                              void* d_out, int out_size, void* d_ws, size_t ws_size,
                              hipStream_t stream) {
    const float* coeff = (const float*)d_in[0];
    const float* noise = (const float*)d_in[1];
    float* out = (float*)d_out;
    dim3 grid(NB * BLOCKS_PER_B);   // 64 * 256 = 16384 blocks, 128 threads each
    fn_kernel<<<grid, 128, 0, stream>>>(coeff, noise, out);
}